// Round 6
// baseline (362.990 us; speedup 1.0000x reference)
//
#include <hip/hip_runtime.h>
#include <hip/hip_bf16.h>

typedef __bf16 bf16;
typedef __attribute__((ext_vector_type(4))) float f32x4;
typedef __attribute__((ext_vector_type(8))) bf16 bf16x8;
typedef __attribute__((ext_vector_type(2))) bf16 bf16x2;

#define NCAMS 6
#define NQ 6400
#define CH 256
#define NH 8
#define NL 3
#define NP 8
#define S_TOT 14784   // 64*176 + 32*88 + 16*44

#if __has_builtin(__builtin_amdgcn_fdot2_f32_bf16) && __has_builtin(__builtin_amdgcn_perm)
#define MSDA_DOT2 1
#else
#define MSDA_DOT2 0
#endif

// ---------------------------------------------------------------- K1: prep = projection + weight packs
// blocks 0..149: projection; blocks 150..285: pack Wvp (8192) / Woap (18432) / Wop (8192)
__global__ __launch_bounds__(256) void k_prep(
    const float* __restrict__ means, const float* __restrict__ cam2ego,
    const float* __restrict__ intrins, const float* __restrict__ post_rots,
    const float* __restrict__ post_trans, const int* __restrict__ img_h,
    const int* __restrict__ img_w,
    const float* __restrict__ W_val, const float* __restrict__ W_off,
    const float* __restrict__ W_attn, const float* __restrict__ W_out,
    float* __restrict__ coor, float* __restrict__ maskf,
    bf16* __restrict__ Wvp, bf16* __restrict__ Woap, bf16* __restrict__ Wop)
{
    int bid = blockIdx.x;
    if (bid < 150) {
        int idx = bid * 256 + threadIdx.x;
        if (idx >= NCAMS * NQ) return;
        int cam = idx / NQ, n = idx % NQ;
        float mx = means[n*3+0], my = means[n*3+1], mz = means[n*3+2];
        const float* M = cam2ego + cam*16;
        float R[3][3], t[3];
        #pragma unroll
        for (int r = 0; r < 3; r++) {
            #pragma unroll
            for (int c = 0; c < 3; c++) R[r][c] = M[r*4+c];
            t[r] = M[r*4+3];
        }
        float dx = mx - t[0], dy = my - t[1], dz = mz - t[2];
        float xc = R[0][0]*dx + R[1][0]*dy + R[2][0]*dz;
        float yc = R[0][1]*dx + R[1][1]*dy + R[2][1]*dz;
        float zc = R[0][2]*dx + R[1][2]*dy + R[2][2]*dz;
        const float* K = intrins + cam*9;
        float ix = K[0]*xc + K[1]*yc + K[2]*zc;
        float iy = K[3]*xc + K[4]*yc + K[5]*zc;
        float iz = K[6]*xc + K[7]*yc + K[8]*zc;
        float px = ix / (iz + 1e-4f), py = iy / (iz + 1e-4f), pz = iz;
        const float* P = post_rots + cam*9;
        const float* T = post_trans + cam*3;
        float vx = P[0]*px + P[1]*py + P[2]*pz + T[0];
        float vy = P[3]*px + P[4]*py + P[5]*pz + T[1];
        float vz = P[6]*px + P[7]*py + P[8]*pz + T[2];
        float cx = vx / (float)img_w[0];
        float cy = vy / (float)img_h[0];
        bool ok = (vz > 0.01f) && (cx > 0.f) && (cx < 1.f) && (cy > 0.f) && (cy < 1.f);
        coor[idx*2+0] = cx;
        coor[idx*2+1] = cy;
        maskf[idx] = ok ? 1.f : 0.f;
        return;
    }
    int flat = (bid - 150) * 256 + threadIdx.x;
    if (flat < 8192) {
        // Wvp: (kc*16+nf)*64+lane <- W_val[kc*32+q*8+j][nf*16+l15]
        int kc = flat >> 10, rem = flat & 1023;
        int nf = rem >> 6, lane = rem & 63;
        int q = lane >> 4, col = nf*16 + (lane & 15);
        bf16x8 v;
        #pragma unroll
        for (int j = 0; j < 8; j++) v[j] = (bf16)W_val[(size_t)(kc*32 + q*8 + j)*256 + col];
        *reinterpret_cast<bf16x8*>(Wvp + (size_t)flat*8) = v;
    } else if (flat < 26624) {
        // Woap: 576 logical cols = [W_off 0..383 | W_attn 384..575]
        int f2 = flat - 8192;
        int kc = f2 / (36*64), rem = f2 % (36*64);
        int nf = rem >> 6, lane = rem & 63;
        int q = lane >> 4, col = nf*16 + (lane & 15);
        bf16x8 v;
        #pragma unroll
        for (int j = 0; j < 8; j++) {
            int k = kc*32 + q*8 + j;
            float x = (col < 384) ? W_off[(size_t)k*384 + col] : W_attn[(size_t)k*192 + (col-384)];
            v[j] = (bf16)x;
        }
        *reinterpret_cast<bf16x8*>(Woap + (size_t)f2*8) = v;
    } else if (flat < 34816) {
        int f3 = flat - 26624;
        int kc = f3 >> 10, rem = f3 & 1023;
        int nf = rem >> 6, lane = rem & 63;
        int q = lane >> 4, col = nf*16 + (lane & 15);
        bf16x8 v;
        #pragma unroll
        for (int j = 0; j < 8; j++) v[j] = (bf16)W_out[(size_t)(kc*32 + q*8 + j)*256 + col];
        *reinterpret_cast<bf16x8*>(Wop + (size_t)f3*8) = v;
    }
}

// ---------------------------------------------------------------- K2: offsets + attn via MFMA (+softmax)
// 400 blocks x 16 queries. A-frags direct from global (feature rows are k-contiguous).
__global__ __launch_bounds__(256) void k_offattn2(
    const float* __restrict__ feature, const bf16* __restrict__ Woap,
    const float* __restrict__ b_off, const float* __restrict__ b_attn,
    float* __restrict__ offs, bf16* __restrict__ attn_out)
{
    __shared__ float lg[16][200];    // logits [m][192], padded
    int t = threadIdx.x, lane = t & 63, w = t >> 6;
    int q = lane >> 4, r16 = lane & 15;
    int n0 = blockIdx.x * 16;

    f32x4 acc[9];
    #pragma unroll
    for (int i = 0; i < 9; i++) acc[i] = (f32x4){0.f,0.f,0.f,0.f};

    const float* arow = feature + (size_t)(n0 + r16)*CH;
    for (int kc = 0; kc < 8; kc++) {
        f32x4 a0 = *reinterpret_cast<const f32x4*>(arow + kc*32 + q*8);
        f32x4 a1 = *reinterpret_cast<const f32x4*>(arow + kc*32 + q*8 + 4);
        bf16x8 afr;
        #pragma unroll
        for (int i = 0; i < 4; i++) { afr[i] = (bf16)a0[i]; afr[4+i] = (bf16)a1[i]; }
        #pragma unroll
        for (int nf9 = 0; nf9 < 9; nf9++) {
            bf16x8 bfr = *reinterpret_cast<const bf16x8*>(Woap + ((size_t)(kc*36 + w*9 + nf9)*64 + lane)*8);
            acc[nf9] = __builtin_amdgcn_mfma_f32_16x16x32_bf16(afr, bfr, acc[nf9], 0, 0, 0);
        }
    }
    #pragma unroll
    for (int nf9 = 0; nf9 < 9; nf9++) {
        int nfg = w*9 + nf9;
        int nglob = nfg*16 + r16;
        if (nfg < 24) {                       // offsets (wave-uniform branch)
            float bias = b_off[nglob];
            #pragma unroll
            for (int r = 0; r < 4; r++)
                offs[(size_t)(n0 + q*4 + r)*384 + nglob] = acc[nf9][r] + bias;
        } else {                              // attn logits -> LDS
            int la = nglob - 384;
            float bias = b_attn[la];
            #pragma unroll
            for (int r = 0; r < 4; r++)
                lg[q*4 + r][la] = acc[nf9][r] + bias;
        }
    }
    __syncthreads();
    if (t < 128) {
        int m = t >> 3, h = t & 7;
        const float* L = &lg[m][h*24];
        float mx = -1e30f;
        #pragma unroll
        for (int j = 0; j < 24; j++) mx = fmaxf(mx, L[j]);
        float e[24]; float s = 0.f;
        #pragma unroll
        for (int j = 0; j < 24; j++) { e[j] = __expf(L[j] - mx); s += e[j]; }
        float inv = 1.f / s;
        #pragma unroll
        for (int j = 0; j < 24; j++) attn_out[(size_t)(n0+m)*192 + h*24 + j] = (bf16)(e[j]*inv);
    }
}

// ---------------------------------------------------------------- K3: value projection GEMM (MFMA bf16)
// value layout: [cam][head][pos][32ch]  (bf16)
__global__ __launch_bounds__(256) void k_valproj(
    const float* __restrict__ f0, const float* __restrict__ f1, const float* __restrict__ f2,
    const float* __restrict__ cams_embeds, const float* __restrict__ level_embeds,
    const bf16* __restrict__ Wvp, const float* __restrict__ b_val, bf16* __restrict__ value)
{
    __shared__ alignas(16) bf16 A[64][48];    // [m][k], padded row 48 (6144 B)
    __shared__ alignas(16) bf16 Cst[16][256]; // epilogue staging stripe (8192 B)
    int bi = blockIdx.x;
    int cam = bi / 231, mb = bi % 231;
    int lvl, local0, HW;
    const float* fp;
    if (mb < 176)      { lvl = 0; local0 = mb*64;        fp = f0; HW = 11264; }
    else if (mb < 220) { lvl = 1; local0 = (mb-176)*64;  fp = f1; HW = 2816;  }
    else               { lvl = 2; local0 = (mb-220)*64;  fp = f2; HW = 704;   }
    int pos0 = (lvl == 0 ? 0 : (lvl == 1 ? 11264 : 14080)) + local0;
    const float* featbase = fp + (size_t)cam*CH*HW + local0;

    int t = threadIdx.x;
    int lane = t & 63, w = t >> 6;
    int kk = t >> 3;            // 0..31 (channel within chunk)
    int m8 = (t & 7) * 8;       // m start
    int q = lane >> 4, r16 = lane & 15;

    f32x4 acc[4][4];
    #pragma unroll
    for (int i = 0; i < 4; i++)
        #pragma unroll
        for (int j = 0; j < 4; j++) acc[i][j] = (f32x4){0.f,0.f,0.f,0.f};

    for (int kc = 0; kc < 8; kc++) {
        __syncthreads();
        int kg = kc*32 + kk;
        float e = cams_embeds[cam*CH + kg] + level_embeds[lvl*CH + kg];
        f32x4 v0 = *reinterpret_cast<const f32x4*>(featbase + (size_t)kg*HW + m8);
        f32x4 v1 = *reinterpret_cast<const f32x4*>(featbase + (size_t)kg*HW + m8 + 4);
        #pragma unroll
        for (int i = 0; i < 4; i++) A[m8+i][kk]   = (bf16)(v0[i] + e);
        #pragma unroll
        for (int i = 0; i < 4; i++) A[m8+4+i][kk] = (bf16)(v1[i] + e);
        __syncthreads();

        bf16x8 bfr[4];
        #pragma unroll
        for (int nf = 0; nf < 4; nf++) {
            int nfg = w*4 + nf;
            bfr[nf] = *reinterpret_cast<const bf16x8*>(Wvp + ((size_t)(kc*16 + nfg)*64 + lane)*8);
        }
        #pragma unroll
        for (int mf = 0; mf < 4; mf++) {
            bf16x8 afr = *reinterpret_cast<const bf16x8*>(&A[mf*16 + r16][q*8]);
            #pragma unroll
            for (int nf = 0; nf < 4; nf++)
                acc[mf][nf] = __builtin_amdgcn_mfma_f32_16x16x32_bf16(afr, bfr[nf], acc[mf][nf], 0, 0, 0);
        }
    }
    // epilogue, per 16-row stripe -> LDS -> coalesced 16B stores
    int orow = t >> 4;                // 0..15
    int ocol = (t & 15) * 16;         // 0..240 step 16
    int ohead = ocol >> 5, och = ocol & 31;
    #pragma unroll
    for (int mf = 0; mf < 4; mf++) {
        __syncthreads();
        #pragma unroll
        for (int nf = 0; nf < 4; nf++) {
            int c = w*64 + nf*16 + r16;
            float bv = b_val[c];
            #pragma unroll
            for (int r = 0; r < 4; r++)
                Cst[q*4 + r][c] = (bf16)(acc[mf][nf][r] + bv);
        }
        __syncthreads();
        int srow = pos0 + mf*16 + orow;
        bf16* dst = value + ((size_t)(cam*NH + ohead)*S_TOT + srow)*32 + och;
        const f32x4* src = reinterpret_cast<const f32x4*>(&Cst[orow][ocol]);
        f32x4 x0 = src[0], x1 = src[1];
        reinterpret_cast<f32x4*>(dst)[0] = x0;
        reinterpret_cast<f32x4*>(dst)[1] = x1;
    }
}

// ---------------------------------------------------------------- K4: MSDA gather (R6: x-pair loads)
// Evidence R2-R5: dur invariant to occupancy (30-74%), batch depth, and asm pipelining =>
// REQUEST-throughput bound (each wave GLD touched 16 scattered 64B segments), not latency.
// Fix: exploit x-adjacency. Corners (x0,y)/(x0+1,y) are contiguous 128B. New lane map
// {cb,p,k2} = x-corner bit(1) x point(3) x 16B-chunk(2); hl looped. Each GLD now covers
// 8 x 128B contiguous spans instead of 16 x 64B scatters -> ~2x fewer memory transactions,
// full 128B line utilization. Border clamps (x1==x0): phase 1 folds w10->w00, w01<-w11 so the
// cb=1 lane's (x0+1) read is weight-0 garbage. Safe overrun: value is no longer last in ws.
// Weights packed per item as {(w00,w01),(w10,w11)}; lane selects by cb; perm pairs (y0,y1)
// data for fdot2 with the selected (wx0,wx1) pair.
__global__ __launch_bounds__(256) void k_msda(
    const float* __restrict__ coor, const float* __restrict__ offs,
    const bf16* __restrict__ attn, const bf16* __restrict__ value,
    const float* __restrict__ maskf, float* __restrict__ slots)
{
    // item = cam*192 + h*24 + lvl*8 + p
    __shared__ int2  s_o[NCAMS*192];     // {y0-row byte addr (x0), y1-row byte addr (x0)} (9216 B)
#if MSDA_DOT2
    __shared__ uint2 s_w[NCAMS*192];     // {pack(w00,w01), pack(w10,w11)} (9216 B)
#else
    __shared__ f32x4 s_w[NCAMS*192];     // {w00,w01,w10,w11}
#endif
    int n = blockIdx.x;
    int t = threadIdx.x;

    // ---------------- phase 1 ----------------
    for (int it = t; it < NCAMS*192; it += 256) {
        int cam = it / 192;
        int r   = it - cam*192;          // h*24 + lvl*8 + p
        int hh  = r / 24;
        int rr  = r - hh*24;
        int lvl = rr >> 3;

        float mk = maskf[cam*NQ + n];
        float cx = coor[(cam*NQ + n)*2 + 0];
        float cy = coor[(cam*NQ + n)*2 + 1];
        float2 o2 = *reinterpret_cast<const float2*>(offs + (size_t)n*384 + r*2);
        float aw = (float)attn[(size_t)n*192 + r] * mk;

        int wi   = (lvl == 0) ? 176 : ((lvl == 1) ? 88 : 44);
        int hi   = (lvl == 0) ? 64  : ((lvl == 1) ? 32 : 16);
        int base = (lvl == 0) ? 0   : ((lvl == 1) ? 11264 : 14080);

        float x = cx*(float)wi + o2.x - 0.5f;
        float y = cy*(float)hi + o2.y - 0.5f;
        float xf = floorf(x), yf = floorf(y);
        float tx = x - xf, ty = y - yf;
        float wm1x = (float)(wi-1), wm1y = (float)(hi-1);
        bool vx0 = (xf >= 0.f)      && (xf <= wm1x);
        bool vx1 = (xf+1.f >= 0.f)  && (xf+1.f <= wm1x);
        bool vy0 = (yf >= 0.f)      && (yf <= wm1y);
        bool vy1 = (yf+1.f >= 0.f)  && (yf+1.f <= wm1y);
        int x0 = (int)fminf(fmaxf(xf,      0.f), wm1x);
        int x1 = (int)fminf(fmaxf(xf+1.f,  0.f), wm1x);
        int y0 = (int)fminf(fmaxf(yf,      0.f), wm1y);
        int y1 = (int)fminf(fmaxf(yf+1.f,  0.f), wm1y);
        float w00 = (1.f-tx)*(1.f-ty)*aw * ((vx0 && vy0) ? 1.f : 0.f);
        float w10 = tx*(1.f-ty)*aw       * ((vx1 && vy0) ? 1.f : 0.f);
        float w01 = (1.f-tx)*ty*aw       * ((vx0 && vy1) ? 1.f : 0.f);
        float w11 = tx*ty*aw             * ((vx1 && vy1) ? 1.f : 0.f);
        if (x1 == x0) {                  // border: both x-corners are the same pixel
            w00 += w10; w10 = 0.f;
            w01 += w11; w11 = 0.f;
        }
        int rowb = (cam*NH + hh)*S_TOT + base;
        s_o[it] = make_int2((rowb + y0*wi + x0)*64, (rowb + y1*wi + x0)*64);
#if MSDA_DOT2
        bf16x2 wx0; wx0[0] = (bf16)w00; wx0[1] = (bf16)w01;   // x0 corner: (y0,y1) weights
        bf16x2 wx1; wx1[0] = (bf16)w10; wx1[1] = (bf16)w11;   // x1 corner
        s_w[it] = make_uint2(__builtin_bit_cast(unsigned, wx0),
                             __builtin_bit_cast(unsigned, wx1));
#else
        s_w[it] = (f32x4){w00, w01, w10, w11};
#endif
    }
    __syncthreads();

    // ---------------- phase 2: x-pair gather ----------------
    int lane = t & 63, wv = t >> 6;
    int cb = lane >> 5;              // x-corner bit (0: x0, 1: x0+1)
    int p  = (lane >> 2) & 7;        // point 0..7
    int k2 = lane & 3;               // 16B chunk within 64B row
    int h0 = wv*2;
    int xoff = cb*64 + k2*16;

    f32x4 aL0 = (f32x4){0.f,0.f,0.f,0.f};   // hl=0 ch j0..3
    f32x4 aH0 = (f32x4){0.f,0.f,0.f,0.f};   // hl=0 ch j4..7
    f32x4 aL1 = (f32x4){0.f,0.f,0.f,0.f};   // hl=1
    f32x4 aH1 = (f32x4){0.f,0.f,0.f,0.f};
    const char* vbyte = (const char*)value;

    int2  co[2][3];
#if MSDA_DOT2
    uint2 cw[2][3];
#else
    f32x4 cw[2][3];
#endif
    #pragma unroll
    for (int hl = 0; hl < 2; hl++)
        #pragma unroll
        for (int l = 0; l < 3; l++) {
            int it = (h0+hl)*24 + l*8 + p;
            co[hl][l] = s_o[it]; cw[hl][l] = s_w[it];
        }

#if MSDA_DOT2
#define CONSUME_UNIT(Ad, Bd, WP, LO, HI) \
    { unsigned wu = cb ? (WP).y : (WP).x; \
      bf16x2 w2 = __builtin_bit_cast(bf16x2, wu); \
      unsigned q0 = __builtin_amdgcn_perm((Bd).x, (Ad).x, 0x05040100u); \
      unsigned q1 = __builtin_amdgcn_perm((Bd).x, (Ad).x, 0x07060302u); \
      unsigned q2 = __builtin_amdgcn_perm((Bd).y, (Ad).y, 0x05040100u); \
      unsigned q3 = __builtin_amdgcn_perm((Bd).y, (Ad).y, 0x07060302u); \
      unsigned q4 = __builtin_amdgcn_perm((Bd).z, (Ad).z, 0x05040100u); \
      unsigned q5 = __builtin_amdgcn_perm((Bd).z, (Ad).z, 0x07060302u); \
      unsigned q6 = __builtin_amdgcn_perm((Bd).w, (Ad).w, 0x05040100u); \
      unsigned q7 = __builtin_amdgcn_perm((Bd).w, (Ad).w, 0x07060302u); \
      LO[0] = __builtin_amdgcn_fdot2_f32_bf16(__builtin_bit_cast(bf16x2, q0), w2, LO[0], false); \
      LO[1] = __builtin_amdgcn_fdot2_f32_bf16(__builtin_bit_cast(bf16x2, q1), w2, LO[1], false); \
      LO[2] = __builtin_amdgcn_fdot2_f32_bf16(__builtin_bit_cast(bf16x2, q2), w2, LO[2], false); \
      LO[3] = __builtin_amdgcn_fdot2_f32_bf16(__builtin_bit_cast(bf16x2, q3), w2, LO[3], false); \
      HI[0] = __builtin_amdgcn_fdot2_f32_bf16(__builtin_bit_cast(bf16x2, q4), w2, HI[0], false); \
      HI[1] = __builtin_amdgcn_fdot2_f32_bf16(__builtin_bit_cast(bf16x2, q5), w2, HI[1], false); \
      HI[2] = __builtin_amdgcn_fdot2_f32_bf16(__builtin_bit_cast(bf16x2, q6), w2, HI[2], false); \
      HI[3] = __builtin_amdgcn_fdot2_f32_bf16(__builtin_bit_cast(bf16x2, q7), w2, HI[3], false); }
#else
#define CONSUME_UNIT(Ad, Bd, WP, LO, HI) \
    { float wA = cb ? (WP).z : (WP).x; \
      float wB = cb ? (WP).w : (WP).y; \
      LO[0] = fmaf(__uint_as_float((Ad).x << 16),         wA, LO[0]); \
      LO[1] = fmaf(__uint_as_float((Ad).x & 0xffff0000u), wA, LO[1]); \
      LO[2] = fmaf(__uint_as_float((Ad).y << 16),         wA, LO[2]); \
      LO[3] = fmaf(__uint_as_float((Ad).y & 0xffff0000u), wA, LO[3]); \
      HI[0] = fmaf(__uint_as_float((Ad).z << 16),         wA, HI[0]); \
      HI[1] = fmaf(__uint_as_float((Ad).z & 0xffff0000u), wA, HI[1]); \
      HI[2] = fmaf(__uint_as_float((Ad).w << 16),         wA, HI[2]); \
      HI[3] = fmaf(__uint_as_float((Ad).w & 0xffff0000u), wA, HI[3]); \
      LO[0] = fmaf(__uint_as_float((Bd).x << 16),         wB, LO[0]); \
      LO[1] = fmaf(__uint_as_float((Bd).x & 0xffff0000u), wB, LO[1]); \
      LO[2] = fmaf(__uint_as_float((Bd).y << 16),         wB, LO[2]); \
      LO[3] = fmaf(__uint_as_float((Bd).y & 0xffff0000u), wB, LO[3]); \
      HI[0] = fmaf(__uint_as_float((Bd).z << 16),         wB, HI[0]); \
      HI[1] = fmaf(__uint_as_float((Bd).z & 0xffff0000u), wB, HI[1]); \
      HI[2] = fmaf(__uint_as_float((Bd).w << 16),         wB, HI[2]); \
      HI[3] = fmaf(__uint_as_float((Bd).w & 0xffff0000u), wB, HI[3]); }
#endif

    #pragma unroll
    for (int cam = 0; cam < NCAMS; cam++) {
        // issue this cam's 12 pair-loads (2 per unit x 6 units)
        uint4 dA[2][3], dB[2][3];
#if MSDA_DOT2
        uint2 wcur[2][3];
#else
        f32x4 wcur[2][3];
#endif
        #pragma unroll
        for (int hl = 0; hl < 2; hl++)
            #pragma unroll
            for (int l = 0; l < 3; l++) {
                dA[hl][l] = *reinterpret_cast<const uint4*>(vbyte + co[hl][l].x + xoff);
                dB[hl][l] = *reinterpret_cast<const uint4*>(vbyte + co[hl][l].y + xoff);
                wcur[hl][l] = cw[hl][l];
            }
        // prefetch next cam's params
        if (cam + 1 < NCAMS) {
            #pragma unroll
            for (int hl = 0; hl < 2; hl++)
                #pragma unroll
                for (int l = 0; l < 3; l++) {
                    int it = (cam+1)*192 + (h0+hl)*24 + l*8 + p;
                    co[hl][l] = s_o[it]; cw[hl][l] = s_w[it];
                }
        }
        // consume
        #pragma unroll
        for (int l = 0; l < 3; l++) {
            CONSUME_UNIT(dA[0][l], dB[0][l], wcur[0][l], aL0, aH0)
            CONSUME_UNIT(dA[1][l], dB[1][l], wcur[1][l], aL1, aH1)
        }
    }
#undef CONSUME_UNIT

    // reduce over p (bits 2..4) and cb (bit 5)
    #pragma unroll
    for (int i = 0; i < 4; i++) {
        aL0[i] += __shfl_xor(aL0[i], 4);  aL0[i] += __shfl_xor(aL0[i], 8);
        aL0[i] += __shfl_xor(aL0[i], 16); aL0[i] += __shfl_xor(aL0[i], 32);
        aH0[i] += __shfl_xor(aH0[i], 4);  aH0[i] += __shfl_xor(aH0[i], 8);
        aH0[i] += __shfl_xor(aH0[i], 16); aH0[i] += __shfl_xor(aH0[i], 32);
        aL1[i] += __shfl_xor(aL1[i], 4);  aL1[i] += __shfl_xor(aL1[i], 8);
        aL1[i] += __shfl_xor(aL1[i], 16); aL1[i] += __shfl_xor(aL1[i], 32);
        aH1[i] += __shfl_xor(aH1[i], 4);  aH1[i] += __shfl_xor(aH1[i], 8);
        aH1[i] += __shfl_xor(aH1[i], 16); aH1[i] += __shfl_xor(aH1[i], 32);
    }
    if ((lane & 60) == 0) {              // p==0 && cb==0, lanes k2=0..3
        float* d0 = slots + (size_t)n*CH + h0*32 + k2*8;
        *reinterpret_cast<f32x4*>(d0)     = aL0;
        *reinterpret_cast<f32x4*>(d0 + 4) = aH0;
        float* d1 = slots + (size_t)n*CH + (h0+1)*32 + k2*8;
        *reinterpret_cast<f32x4*>(d1)     = aL1;
        *reinterpret_cast<f32x4*>(d1 + 4) = aH1;
    }
}

// ---------------------------------------------------------------- K6: mask-mean + out proj (MFMA) + residual + LN
// 400 blocks x 16 queries; mask-mean folded into A-frag scale; fused LN.
__global__ __launch_bounds__(256) void k_final2(
    const float* __restrict__ slots, const float* __restrict__ maskf,
    const bf16* __restrict__ Wop, const float* __restrict__ b_out,
    const float* __restrict__ feature, const float* __restrict__ ln_g,
    const float* __restrict__ ln_b, float* __restrict__ out)
{
    __shared__ float yb[16][264];    // y rows, padded (264) for conflict-free scattered writes
    int t = threadIdx.x, lane = t & 63, w = t >> 6;
    int q = lane >> 4, r16 = lane & 15;
    int n0 = blockIdx.x * 16;

    float msum = 0.f;
    #pragma unroll
    for (int cam = 0; cam < NCAMS; cam++) msum += maskf[cam*NQ + n0 + r16];
    float inv = 1.f / fmaxf(msum, 1.f);

    f32x4 acc[4];
    #pragma unroll
    for (int i = 0; i < 4; i++) acc[i] = (f32x4){0.f,0.f,0.f,0.f};

    const float* srow = slots + (size_t)(n0 + r16)*CH;
    for (int kc = 0; kc < 8; kc++) {
        f32x4 a0 = *reinterpret_cast<const f32x4*>(srow + kc*32 + q*8);
        f32x4 a1 = *reinterpret_cast<const f32x4*>(srow + kc*32 + q*8 + 4);
        bf16x8 afr;
        #pragma unroll
        for (int i = 0; i < 4; i++) { afr[i] = (bf16)(a0[i]*inv); afr[4+i] = (bf16)(a1[i]*inv); }
        #pragma unroll
        for (int nf = 0; nf < 4; nf++) {
            bf16x8 bfr = *reinterpret_cast<const bf16x8*>(Wop + ((size_t)(kc*16 + w*4 + nf)*64 + lane)*8);
            acc[nf] = __builtin_amdgcn_mfma_f32_16x16x32_bf16(afr, bfr, acc[nf], 0, 0, 0);
        }
    }
    #pragma unroll
    for (int nf = 0; nf < 4; nf++) {
        int c = (w*4 + nf)*16 + r16;
        float bias = b_out[c];
        #pragma unroll
        for (int r = 0; r < 4; r++) {
            int m = q*4 + r;
            yb[m][c] = acc[nf][r] + bias + feature[(size_t)(n0+m)*CH + c];
        }
    }
    __syncthreads();
    // LN: row = t>>4 (16 rows), l16 = t&15 each sums 16 elements
    int row = t >> 4, l16 = t & 15;
    int c0 = l16 * 16;
    float s = 0.f, s2 = 0.f;
    #pragma unroll
    for (int j = 0; j < 16; j++) {
        float v = yb[row][c0 + j];
        s += v; s2 += v*v;
    }
    #pragma unroll
    for (int off = 1; off < 16; off <<= 1) {
        s  += __shfl_xor(s, off);
        s2 += __shfl_xor(s2, off);
    }
    float mu = s / 256.f;
    float rsig = rsqrtf(s2 / 256.f - mu*mu + 1e-5f);
    float* orow = out + (size_t)(n0 + row)*CH + c0;
    #pragma unroll
    for (int j4 = 0; j4 < 4; j4++) {
        f32x4 o;
        #pragma unroll
        for (int i = 0; i < 4; i++) {
            int c = c0 + j4*4 + i;
            o[i] = (yb[row][c] - mu) * rsig * ln_g[c] + ln_b[c];
        }
        *reinterpret_cast<f32x4*>(orow + j4*4) = o;
    }
}

// ---------------------------------------------------------------- launch
extern "C" void kernel_launch(void* const* d_in, const int* in_sizes, int n_in,
                              void* d_out, int out_size, void* d_ws, size_t ws_size,
                              hipStream_t stream)
{
    const float* means       = (const float*)d_in[0];
    const float* feature     = (const float*)d_in[1];
    const float* feat0       = (const float*)d_in[2];
    const float* feat1       = (const float*)d_in[3];
    const float* feat2       = (const float*)d_in[4];
    const float* cam2ego     = (const float*)d_in[5];
    const float* intrins     = (const float*)d_in[6];
    const float* post_rots   = (const float*)d_in[7];
    const float* post_trans  = (const float*)d_in[8];
    const float* W_off       = (const float*)d_in[9];
    const float* b_off       = (const float*)d_in[10];
    const float* W_attn      = (const float*)d_in[11];
    const float* b_attn      = (const float*)d_in[12];
    const float* W_val       = (const float*)d_in[13];
    const float* b_val       = (const float*)d_in[14];
    const float* W_out       = (const float*)d_in[15];
    const float* b_out       = (const float*)d_in[16];
    const float* cams_embeds = (const float*)d_in[17];
    const float* level_embeds= (const float*)d_in[18];
    const float* ln_g        = (const float*)d_in[19];
    const float* ln_b        = (const float*)d_in[20];
    const int*   img_h       = (const int*)d_in[21];
    const int*   img_w       = (const int*)d_in[22];

    // workspace layout (total 65,275,904 B = 62.3 MiB)
    // NOTE: value is deliberately NOT last -- k_msda's x-pair loads may read up to 64B past the
    // final value row (weight-0 lanes at image borders); slots follows so the read stays in-bounds.
    char* ws = (char*)d_ws;
    float* coor  = (float*)(ws + 0);           //  6*6400*2 f32      =   307,200
    float* maskf = (float*)(ws + 307200);      //  6*6400 f32        =   153,600
    float* offs  = (float*)(ws + 460800);      //  6400*384 f32      = 9,830,400
    bf16*  attn  = (bf16*) (ws + 10291200);    //  6400*192 bf16     = 2,457,600
    bf16*  Wvp   = (bf16*) (ws + 12748800);    //  256*256 bf16      =   131,072
    bf16*  Woap  = (bf16*) (ws + 12879872);    //  256*576 bf16      =   294,912
    bf16*  Wop   = (bf16*) (ws + 13174784);    //  256*256 bf16      =   131,072
    bf16*  value = (bf16*) (ws + 13305856);    //  6*8*14784*32 bf16 = 45,416,448
    float* slots = (float*)(ws + 58722304);    //  6400*256 f32      = 6,553,600
    if (ws_size < 65275904u) return;

    k_prep    <<<286, 256, 0, stream>>>(means, cam2ego, intrins, post_rots, post_trans,
                                        img_h, img_w, W_val, W_off, W_attn, W_out,
                                        coor, maskf, Wvp, Woap, Wop);
    k_offattn2<<<400, 256, 0, stream>>>(feature, Woap, b_off, b_attn, offs, attn);
    k_valproj <<<1386, 256, 0, stream>>>(feat0, feat1, feat2, cams_embeds, level_embeds, Wvp, b_val, value);
    k_msda    <<<6400, 256, 0, stream>>>(coor, offs, attn, value, maskf, slots);
    k_final2  <<<400, 256, 0, stream>>>(slots, maskf, Wop, b_out, feature, ln_g, ln_b, (float*)d_out);
}

// Round 7
// 297.078 us; speedup vs baseline: 1.2219x; 1.2219x over previous
//
#include <hip/hip_runtime.h>
#include <hip/hip_bf16.h>

typedef __bf16 bf16;
typedef __attribute__((ext_vector_type(4))) float f32x4;
typedef __attribute__((ext_vector_type(8))) bf16 bf16x8;
typedef __attribute__((ext_vector_type(2))) bf16 bf16x2;

#define NCAMS 6
#define NQ 6400
#define CH 256
#define NH 8
#define NL 3
#define NP 8
#define S_TOT 14784   // 64*176 + 32*88 + 16*44

#if __has_builtin(__builtin_amdgcn_fdot2_f32_bf16) && __has_builtin(__builtin_amdgcn_perm)
#define MSDA_DOT2 1
#else
#define MSDA_DOT2 0
#endif

// ---------------------------------------------------------------- K1: prep = projection + weight packs
// blocks 0..149: projection; blocks 150..285: pack Wvp (8192) / Woap (18432) / Wop (8192)
__global__ __launch_bounds__(256) void k_prep(
    const float* __restrict__ means, const float* __restrict__ cam2ego,
    const float* __restrict__ intrins, const float* __restrict__ post_rots,
    const float* __restrict__ post_trans, const int* __restrict__ img_h,
    const int* __restrict__ img_w,
    const float* __restrict__ W_val, const float* __restrict__ W_off,
    const float* __restrict__ W_attn, const float* __restrict__ W_out,
    float* __restrict__ coor, float* __restrict__ maskf,
    bf16* __restrict__ Wvp, bf16* __restrict__ Woap, bf16* __restrict__ Wop)
{
    int bid = blockIdx.x;
    if (bid < 150) {
        int idx = bid * 256 + threadIdx.x;
        if (idx >= NCAMS * NQ) return;
        int cam = idx / NQ, n = idx % NQ;
        float mx = means[n*3+0], my = means[n*3+1], mz = means[n*3+2];
        const float* M = cam2ego + cam*16;
        float R[3][3], t[3];
        #pragma unroll
        for (int r = 0; r < 3; r++) {
            #pragma unroll
            for (int c = 0; c < 3; c++) R[r][c] = M[r*4+c];
            t[r] = M[r*4+3];
        }
        float dx = mx - t[0], dy = my - t[1], dz = mz - t[2];
        float xc = R[0][0]*dx + R[1][0]*dy + R[2][0]*dz;
        float yc = R[0][1]*dx + R[1][1]*dy + R[2][1]*dz;
        float zc = R[0][2]*dx + R[1][2]*dy + R[2][2]*dz;
        const float* K = intrins + cam*9;
        float ix = K[0]*xc + K[1]*yc + K[2]*zc;
        float iy = K[3]*xc + K[4]*yc + K[5]*zc;
        float iz = K[6]*xc + K[7]*yc + K[8]*zc;
        float px = ix / (iz + 1e-4f), py = iy / (iz + 1e-4f), pz = iz;
        const float* P = post_rots + cam*9;
        const float* T = post_trans + cam*3;
        float vx = P[0]*px + P[1]*py + P[2]*pz + T[0];
        float vy = P[3]*px + P[4]*py + P[5]*pz + T[1];
        float vz = P[6]*px + P[7]*py + P[8]*pz + T[2];
        float cx = vx / (float)img_w[0];
        float cy = vy / (float)img_h[0];
        bool ok = (vz > 0.01f) && (cx > 0.f) && (cx < 1.f) && (cy > 0.f) && (cy < 1.f);
        coor[idx*2+0] = cx;
        coor[idx*2+1] = cy;
        maskf[idx] = ok ? 1.f : 0.f;
        return;
    }
    int flat = (bid - 150) * 256 + threadIdx.x;
    if (flat < 8192) {
        // Wvp: (kc*16+nf)*64+lane <- W_val[kc*32+q*8+j][nf*16+l15]
        int kc = flat >> 10, rem = flat & 1023;
        int nf = rem >> 6, lane = rem & 63;
        int q = lane >> 4, col = nf*16 + (lane & 15);
        bf16x8 v;
        #pragma unroll
        for (int j = 0; j < 8; j++) v[j] = (bf16)W_val[(size_t)(kc*32 + q*8 + j)*256 + col];
        *reinterpret_cast<bf16x8*>(Wvp + (size_t)flat*8) = v;
    } else if (flat < 26624) {
        // Woap: 576 logical cols = [W_off 0..383 | W_attn 384..575]
        int f2 = flat - 8192;
        int kc = f2 / (36*64), rem = f2 % (36*64);
        int nf = rem >> 6, lane = rem & 63;
        int q = lane >> 4, col = nf*16 + (lane & 15);
        bf16x8 v;
        #pragma unroll
        for (int j = 0; j < 8; j++) {
            int k = kc*32 + q*8 + j;
            float x = (col < 384) ? W_off[(size_t)k*384 + col] : W_attn[(size_t)k*192 + (col-384)];
            v[j] = (bf16)x;
        }
        *reinterpret_cast<bf16x8*>(Woap + (size_t)f2*8) = v;
    } else if (flat < 34816) {
        int f3 = flat - 26624;
        int kc = f3 >> 10, rem = f3 & 1023;
        int nf = rem >> 6, lane = rem & 63;
        int q = lane >> 4, col = nf*16 + (lane & 15);
        bf16x8 v;
        #pragma unroll
        for (int j = 0; j < 8; j++) v[j] = (bf16)W_out[(size_t)(kc*32 + q*8 + j)*256 + col];
        *reinterpret_cast<bf16x8*>(Wop + (size_t)f3*8) = v;
    }
}

// ---------------------------------------------------------------- K2: offsets + attn via MFMA (+softmax)
// 400 blocks x 16 queries. A-frags direct from global (feature rows are k-contiguous).
__global__ __launch_bounds__(256) void k_offattn2(
    const float* __restrict__ feature, const bf16* __restrict__ Woap,
    const float* __restrict__ b_off, const float* __restrict__ b_attn,
    float* __restrict__ offs, bf16* __restrict__ attn_out)
{
    __shared__ float lg[16][200];    // logits [m][192], padded
    int t = threadIdx.x, lane = t & 63, w = t >> 6;
    int q = lane >> 4, r16 = lane & 15;
    int n0 = blockIdx.x * 16;

    f32x4 acc[9];
    #pragma unroll
    for (int i = 0; i < 9; i++) acc[i] = (f32x4){0.f,0.f,0.f,0.f};

    const float* arow = feature + (size_t)(n0 + r16)*CH;
    for (int kc = 0; kc < 8; kc++) {
        f32x4 a0 = *reinterpret_cast<const f32x4*>(arow + kc*32 + q*8);
        f32x4 a1 = *reinterpret_cast<const f32x4*>(arow + kc*32 + q*8 + 4);
        bf16x8 afr;
        #pragma unroll
        for (int i = 0; i < 4; i++) { afr[i] = (bf16)a0[i]; afr[4+i] = (bf16)a1[i]; }
        #pragma unroll
        for (int nf9 = 0; nf9 < 9; nf9++) {
            bf16x8 bfr = *reinterpret_cast<const bf16x8*>(Woap + ((size_t)(kc*36 + w*9 + nf9)*64 + lane)*8);
            acc[nf9] = __builtin_amdgcn_mfma_f32_16x16x32_bf16(afr, bfr, acc[nf9], 0, 0, 0);
        }
    }
    #pragma unroll
    for (int nf9 = 0; nf9 < 9; nf9++) {
        int nfg = w*9 + nf9;
        int nglob = nfg*16 + r16;
        if (nfg < 24) {                       // offsets (wave-uniform branch)
            float bias = b_off[nglob];
            #pragma unroll
            for (int r = 0; r < 4; r++)
                offs[(size_t)(n0 + q*4 + r)*384 + nglob] = acc[nf9][r] + bias;
        } else {                              // attn logits -> LDS
            int la = nglob - 384;
            float bias = b_attn[la];
            #pragma unroll
            for (int r = 0; r < 4; r++)
                lg[q*4 + r][la] = acc[nf9][r] + bias;
        }
    }
    __syncthreads();
    if (t < 128) {
        int m = t >> 3, h = t & 7;
        const float* L = &lg[m][h*24];
        float mx = -1e30f;
        #pragma unroll
        for (int j = 0; j < 24; j++) mx = fmaxf(mx, L[j]);
        float e[24]; float s = 0.f;
        #pragma unroll
        for (int j = 0; j < 24; j++) { e[j] = __expf(L[j] - mx); s += e[j]; }
        float inv = 1.f / s;
        #pragma unroll
        for (int j = 0; j < 24; j++) attn_out[(size_t)(n0+m)*192 + h*24 + j] = (bf16)(e[j]*inv);
    }
}

// ---------------------------------------------------------------- K3: value projection GEMM (MFMA bf16)
// value layout: [cam][head][pos][32ch]  (bf16)
__global__ __launch_bounds__(256) void k_valproj(
    const float* __restrict__ f0, const float* __restrict__ f1, const float* __restrict__ f2,
    const float* __restrict__ cams_embeds, const float* __restrict__ level_embeds,
    const bf16* __restrict__ Wvp, const float* __restrict__ b_val, bf16* __restrict__ value)
{
    __shared__ alignas(16) bf16 A[64][48];    // [m][k], padded row 48 (6144 B)
    __shared__ alignas(16) bf16 Cst[16][256]; // epilogue staging stripe (8192 B)
    int bi = blockIdx.x;
    int cam = bi / 231, mb = bi % 231;
    int lvl, local0, HW;
    const float* fp;
    if (mb < 176)      { lvl = 0; local0 = mb*64;        fp = f0; HW = 11264; }
    else if (mb < 220) { lvl = 1; local0 = (mb-176)*64;  fp = f1; HW = 2816;  }
    else               { lvl = 2; local0 = (mb-220)*64;  fp = f2; HW = 704;   }
    int pos0 = (lvl == 0 ? 0 : (lvl == 1 ? 11264 : 14080)) + local0;
    const float* featbase = fp + (size_t)cam*CH*HW + local0;

    int t = threadIdx.x;
    int lane = t & 63, w = t >> 6;
    int kk = t >> 3;            // 0..31 (channel within chunk)
    int m8 = (t & 7) * 8;       // m start
    int q = lane >> 4, r16 = lane & 15;

    f32x4 acc[4][4];
    #pragma unroll
    for (int i = 0; i < 4; i++)
        #pragma unroll
        for (int j = 0; j < 4; j++) acc[i][j] = (f32x4){0.f,0.f,0.f,0.f};

    for (int kc = 0; kc < 8; kc++) {
        __syncthreads();
        int kg = kc*32 + kk;
        float e = cams_embeds[cam*CH + kg] + level_embeds[lvl*CH + kg];
        f32x4 v0 = *reinterpret_cast<const f32x4*>(featbase + (size_t)kg*HW + m8);
        f32x4 v1 = *reinterpret_cast<const f32x4*>(featbase + (size_t)kg*HW + m8 + 4);
        #pragma unroll
        for (int i = 0; i < 4; i++) A[m8+i][kk]   = (bf16)(v0[i] + e);
        #pragma unroll
        for (int i = 0; i < 4; i++) A[m8+4+i][kk] = (bf16)(v1[i] + e);
        __syncthreads();

        bf16x8 bfr[4];
        #pragma unroll
        for (int nf = 0; nf < 4; nf++) {
            int nfg = w*4 + nf;
            bfr[nf] = *reinterpret_cast<const bf16x8*>(Wvp + ((size_t)(kc*16 + nfg)*64 + lane)*8);
        }
        #pragma unroll
        for (int mf = 0; mf < 4; mf++) {
            bf16x8 afr = *reinterpret_cast<const bf16x8*>(&A[mf*16 + r16][q*8]);
            #pragma unroll
            for (int nf = 0; nf < 4; nf++)
                acc[mf][nf] = __builtin_amdgcn_mfma_f32_16x16x32_bf16(afr, bfr[nf], acc[mf][nf], 0, 0, 0);
        }
    }
    // epilogue, per 16-row stripe -> LDS -> coalesced 16B stores
    int orow = t >> 4;                // 0..15
    int ocol = (t & 15) * 16;         // 0..240 step 16
    int ohead = ocol >> 5, och = ocol & 31;
    #pragma unroll
    for (int mf = 0; mf < 4; mf++) {
        __syncthreads();
        #pragma unroll
        for (int nf = 0; nf < 4; nf++) {
            int c = w*64 + nf*16 + r16;
            float bv = b_val[c];
            #pragma unroll
            for (int r = 0; r < 4; r++)
                Cst[q*4 + r][c] = (bf16)(acc[mf][nf][r] + bv);
        }
        __syncthreads();
        int srow = pos0 + mf*16 + orow;
        bf16* dst = value + ((size_t)(cam*NH + ohead)*S_TOT + srow)*32 + och;
        const f32x4* src = reinterpret_cast<const f32x4*>(&Cst[orow][ocol]);
        f32x4 x0 = src[0], x1 = src[1];
        reinterpret_cast<f32x4*>(dst)[0] = x0;
        reinterpret_cast<f32x4*>(dst)[1] = x1;
    }
}

// ---------------------------------------------------------------- K4: MSDA gather (R7: x-pair, scalar-clean)
// R6's x-pair attempt spilled its gather arrays to scratch (WRITE_SIZE 6.4MB -> 253MB -> dur 168us):
// the experiment never ran as designed. This round: identical phase 1 (x-pair packing, verified
// correct by R6's pass), phase 2 rewritten with ONLY named scalar registers -- no arrays, no
// cross-cam prefetch (R2-R5: scheduling depth is irrelevant, the kernel is request-throughput
// bound). Each load instruction covers 8 x 128B contiguous x-pair spans instead of 16 x 64B
// scatters -> halves 128B-line visits per request. Live set ~52 VGPR, no spill possible.
__global__ __launch_bounds__(256) void k_msda(
    const float* __restrict__ coor, const float* __restrict__ offs,
    const bf16* __restrict__ attn, const bf16* __restrict__ value,
    const float* __restrict__ maskf, float* __restrict__ slots)
{
    // item = cam*192 + h*24 + lvl*8 + p
    __shared__ int2  s_o[NCAMS*192];     // {y0-row byte addr (x0), y1-row byte addr (x0)} (9216 B)
#if MSDA_DOT2
    __shared__ uint2 s_w[NCAMS*192];     // {pack(w00,w01), pack(w10,w11)} (9216 B)
#else
    __shared__ f32x4 s_w[NCAMS*192];     // {w00,w01,w10,w11}
#endif
    int n = blockIdx.x;
    int t = threadIdx.x;

    // ---------------- phase 1 ----------------
    for (int it = t; it < NCAMS*192; it += 256) {
        int cam = it / 192;
        int r   = it - cam*192;          // h*24 + lvl*8 + p
        int hh  = r / 24;
        int rr  = r - hh*24;
        int lvl = rr >> 3;

        float mk = maskf[cam*NQ + n];
        float cx = coor[(cam*NQ + n)*2 + 0];
        float cy = coor[(cam*NQ + n)*2 + 1];
        float2 o2 = *reinterpret_cast<const float2*>(offs + (size_t)n*384 + r*2);
        float aw = (float)attn[(size_t)n*192 + r] * mk;

        int wi   = (lvl == 0) ? 176 : ((lvl == 1) ? 88 : 44);
        int hi   = (lvl == 0) ? 64  : ((lvl == 1) ? 32 : 16);
        int base = (lvl == 0) ? 0   : ((lvl == 1) ? 11264 : 14080);

        float x = cx*(float)wi + o2.x - 0.5f;
        float y = cy*(float)hi + o2.y - 0.5f;
        float xf = floorf(x), yf = floorf(y);
        float tx = x - xf, ty = y - yf;
        float wm1x = (float)(wi-1), wm1y = (float)(hi-1);
        bool vx0 = (xf >= 0.f)      && (xf <= wm1x);
        bool vx1 = (xf+1.f >= 0.f)  && (xf+1.f <= wm1x);
        bool vy0 = (yf >= 0.f)      && (yf <= wm1y);
        bool vy1 = (yf+1.f >= 0.f)  && (yf+1.f <= wm1y);
        int x0 = (int)fminf(fmaxf(xf,      0.f), wm1x);
        int x1 = (int)fminf(fmaxf(xf+1.f,  0.f), wm1x);
        int y0 = (int)fminf(fmaxf(yf,      0.f), wm1y);
        int y1 = (int)fminf(fmaxf(yf+1.f,  0.f), wm1y);
        float w00 = (1.f-tx)*(1.f-ty)*aw * ((vx0 && vy0) ? 1.f : 0.f);
        float w10 = tx*(1.f-ty)*aw       * ((vx1 && vy0) ? 1.f : 0.f);
        float w01 = (1.f-tx)*ty*aw       * ((vx0 && vy1) ? 1.f : 0.f);
        float w11 = tx*ty*aw             * ((vx1 && vy1) ? 1.f : 0.f);
        if (x1 == x0) {                  // border: both x-corners are the same pixel
            w00 += w10; w10 = 0.f;
            w01 += w11; w11 = 0.f;
        }
        int rowb = (cam*NH + hh)*S_TOT + base;
        s_o[it] = make_int2((rowb + y0*wi + x0)*64, (rowb + y1*wi + x0)*64);
#if MSDA_DOT2
        bf16x2 wx0; wx0[0] = (bf16)w00; wx0[1] = (bf16)w01;   // x0 corner: (y0,y1) weights
        bf16x2 wx1; wx1[0] = (bf16)w10; wx1[1] = (bf16)w11;   // x1 corner
        s_w[it] = make_uint2(__builtin_bit_cast(unsigned, wx0),
                             __builtin_bit_cast(unsigned, wx1));
#else
        s_w[it] = (f32x4){w00, w01, w10, w11};
#endif
    }
    __syncthreads();

    // ---------------- phase 2: x-pair gather, named scalars only ----------------
    int lane = t & 63, wv = t >> 6;
    int cb = lane >> 5;              // x-corner bit (0: x0, 1: x0+1)
    int p  = (lane >> 2) & 7;        // point 0..7
    int k2 = lane & 3;               // 16B chunk within 64B row
    int h0 = wv*2;
    int xoff = cb*64 + k2*16;

    f32x4 aL0 = (f32x4){0.f,0.f,0.f,0.f};   // hl=0 ch j0..3
    f32x4 aH0 = (f32x4){0.f,0.f,0.f,0.f};   // hl=0 ch j4..7
    f32x4 aL1 = (f32x4){0.f,0.f,0.f,0.f};   // hl=1
    f32x4 aH1 = (f32x4){0.f,0.f,0.f,0.f};
    const char* vbyte = (const char*)value;

#if MSDA_DOT2
#define CONSUME_UNIT(Ad, Bd, WP, LO, HI) \
    { unsigned wu = cb ? (WP).y : (WP).x; \
      bf16x2 w2 = __builtin_bit_cast(bf16x2, wu); \
      unsigned q0 = __builtin_amdgcn_perm((Bd).x, (Ad).x, 0x05040100u); \
      unsigned q1 = __builtin_amdgcn_perm((Bd).x, (Ad).x, 0x07060302u); \
      unsigned q2 = __builtin_amdgcn_perm((Bd).y, (Ad).y, 0x05040100u); \
      unsigned q3 = __builtin_amdgcn_perm((Bd).y, (Ad).y, 0x07060302u); \
      unsigned q4 = __builtin_amdgcn_perm((Bd).z, (Ad).z, 0x05040100u); \
      unsigned q5 = __builtin_amdgcn_perm((Bd).z, (Ad).z, 0x07060302u); \
      unsigned q6 = __builtin_amdgcn_perm((Bd).w, (Ad).w, 0x05040100u); \
      unsigned q7 = __builtin_amdgcn_perm((Bd).w, (Ad).w, 0x07060302u); \
      LO[0] = __builtin_amdgcn_fdot2_f32_bf16(__builtin_bit_cast(bf16x2, q0), w2, LO[0], false); \
      LO[1] = __builtin_amdgcn_fdot2_f32_bf16(__builtin_bit_cast(bf16x2, q1), w2, LO[1], false); \
      LO[2] = __builtin_amdgcn_fdot2_f32_bf16(__builtin_bit_cast(bf16x2, q2), w2, LO[2], false); \
      LO[3] = __builtin_amdgcn_fdot2_f32_bf16(__builtin_bit_cast(bf16x2, q3), w2, LO[3], false); \
      HI[0] = __builtin_amdgcn_fdot2_f32_bf16(__builtin_bit_cast(bf16x2, q4), w2, HI[0], false); \
      HI[1] = __builtin_amdgcn_fdot2_f32_bf16(__builtin_bit_cast(bf16x2, q5), w2, HI[1], false); \
      HI[2] = __builtin_amdgcn_fdot2_f32_bf16(__builtin_bit_cast(bf16x2, q6), w2, HI[2], false); \
      HI[3] = __builtin_amdgcn_fdot2_f32_bf16(__builtin_bit_cast(bf16x2, q7), w2, HI[3], false); }
#else
#define CONSUME_UNIT(Ad, Bd, WP, LO, HI) \
    { float wA = cb ? (WP).z : (WP).x; \
      float wB = cb ? (WP).w : (WP).y; \
      LO[0] = fmaf(__uint_as_float((Ad).x << 16),         wA, LO[0]); \
      LO[1] = fmaf(__uint_as_float((Ad).x & 0xffff0000u), wA, LO[1]); \
      LO[2] = fmaf(__uint_as_float((Ad).y << 16),         wA, LO[2]); \
      LO[3] = fmaf(__uint_as_float((Ad).y & 0xffff0000u), wA, LO[3]); \
      HI[0] = fmaf(__uint_as_float((Ad).z << 16),         wA, HI[0]); \
      HI[1] = fmaf(__uint_as_float((Ad).z & 0xffff0000u), wA, HI[1]); \
      HI[2] = fmaf(__uint_as_float((Ad).w << 16),         wA, HI[2]); \
      HI[3] = fmaf(__uint_as_float((Ad).w & 0xffff0000u), wA, HI[3]); \
      LO[0] = fmaf(__uint_as_float((Bd).x << 16),         wB, LO[0]); \
      LO[1] = fmaf(__uint_as_float((Bd).x & 0xffff0000u), wB, LO[1]); \
      LO[2] = fmaf(__uint_as_float((Bd).y << 16),         wB, LO[2]); \
      LO[3] = fmaf(__uint_as_float((Bd).y & 0xffff0000u), wB, LO[3]); \
      HI[0] = fmaf(__uint_as_float((Bd).z << 16),         wB, HI[0]); \
      HI[1] = fmaf(__uint_as_float((Bd).z & 0xffff0000u), wB, HI[1]); \
      HI[2] = fmaf(__uint_as_float((Bd).w << 16),         wB, HI[2]); \
      HI[3] = fmaf(__uint_as_float((Bd).w & 0xffff0000u), wB, HI[3]); }
#endif

    // One macro per (cam, hl): 6 independent pair-loads issued together (named scalars),
    // one implicit waitcnt, then consume. No arrays -> no scratch.
#if MSDA_DOT2
#define GATHER_HL(CAM, HL, ACCL, ACCH) { \
    int itb = (CAM)*192 + (h0+(HL))*24 + p; \
    int2 o0 = s_o[itb]; int2 o1 = s_o[itb+8]; int2 o2v = s_o[itb+16]; \
    uint2 w0 = s_w[itb]; uint2 w1 = s_w[itb+8]; uint2 w2v = s_w[itb+16]; \
    uint4 A0 = *reinterpret_cast<const uint4*>(vbyte + o0.x + xoff); \
    uint4 B0 = *reinterpret_cast<const uint4*>(vbyte + o0.y + xoff); \
    uint4 A1 = *reinterpret_cast<const uint4*>(vbyte + o1.x + xoff); \
    uint4 B1 = *reinterpret_cast<const uint4*>(vbyte + o1.y + xoff); \
    uint4 A2 = *reinterpret_cast<const uint4*>(vbyte + o2v.x + xoff); \
    uint4 B2 = *reinterpret_cast<const uint4*>(vbyte + o2v.y + xoff); \
    CONSUME_UNIT(A0, B0, w0,  ACCL, ACCH) \
    CONSUME_UNIT(A1, B1, w1,  ACCL, ACCH) \
    CONSUME_UNIT(A2, B2, w2v, ACCL, ACCH) }
#else
#define GATHER_HL(CAM, HL, ACCL, ACCH) { \
    int itb = (CAM)*192 + (h0+(HL))*24 + p; \
    int2 o0 = s_o[itb]; int2 o1 = s_o[itb+8]; int2 o2v = s_o[itb+16]; \
    f32x4 w0 = s_w[itb]; f32x4 w1 = s_w[itb+8]; f32x4 w2v = s_w[itb+16]; \
    uint4 A0 = *reinterpret_cast<const uint4*>(vbyte + o0.x + xoff); \
    uint4 B0 = *reinterpret_cast<const uint4*>(vbyte + o0.y + xoff); \
    uint4 A1 = *reinterpret_cast<const uint4*>(vbyte + o1.x + xoff); \
    uint4 B1 = *reinterpret_cast<const uint4*>(vbyte + o1.y + xoff); \
    uint4 A2 = *reinterpret_cast<const uint4*>(vbyte + o2v.x + xoff); \
    uint4 B2 = *reinterpret_cast<const uint4*>(vbyte + o2v.y + xoff); \
    CONSUME_UNIT(A0, B0, w0,  ACCL, ACCH) \
    CONSUME_UNIT(A1, B1, w1,  ACCL, ACCH) \
    CONSUME_UNIT(A2, B2, w2v, ACCL, ACCH) }
#endif

    #pragma unroll
    for (int cam = 0; cam < NCAMS; cam++) {
        GATHER_HL(cam, 0, aL0, aH0)
        GATHER_HL(cam, 1, aL1, aH1)
    }
#undef GATHER_HL
#undef CONSUME_UNIT

    // reduce over p (bits 2..4) and cb (bit 5)
    #pragma unroll
    for (int i = 0; i < 4; i++) {
        aL0[i] += __shfl_xor(aL0[i], 4);  aL0[i] += __shfl_xor(aL0[i], 8);
        aL0[i] += __shfl_xor(aL0[i], 16); aL0[i] += __shfl_xor(aL0[i], 32);
        aH0[i] += __shfl_xor(aH0[i], 4);  aH0[i] += __shfl_xor(aH0[i], 8);
        aH0[i] += __shfl_xor(aH0[i], 16); aH0[i] += __shfl_xor(aH0[i], 32);
        aL1[i] += __shfl_xor(aL1[i], 4);  aL1[i] += __shfl_xor(aL1[i], 8);
        aL1[i] += __shfl_xor(aL1[i], 16); aL1[i] += __shfl_xor(aL1[i], 32);
        aH1[i] += __shfl_xor(aH1[i], 4);  aH1[i] += __shfl_xor(aH1[i], 8);
        aH1[i] += __shfl_xor(aH1[i], 16); aH1[i] += __shfl_xor(aH1[i], 32);
    }
    if ((lane & 60) == 0) {              // p==0 && cb==0, lanes k2=0..3
        float* d0 = slots + (size_t)n*CH + h0*32 + k2*8;
        *reinterpret_cast<f32x4*>(d0)     = aL0;
        *reinterpret_cast<f32x4*>(d0 + 4) = aH0;
        float* d1 = slots + (size_t)n*CH + (h0+1)*32 + k2*8;
        *reinterpret_cast<f32x4*>(d1)     = aL1;
        *reinterpret_cast<f32x4*>(d1 + 4) = aH1;
    }
}

// ---------------------------------------------------------------- K6: mask-mean + out proj (MFMA) + residual + LN
// 400 blocks x 16 queries; mask-mean folded into A-frag scale; fused LN.
__global__ __launch_bounds__(256) void k_final2(
    const float* __restrict__ slots, const float* __restrict__ maskf,
    const bf16* __restrict__ Wop, const float* __restrict__ b_out,
    const float* __restrict__ feature, const float* __restrict__ ln_g,
    const float* __restrict__ ln_b, float* __restrict__ out)
{
    __shared__ float yb[16][264];    // y rows, padded (264) for conflict-free scattered writes
    int t = threadIdx.x, lane = t & 63, w = t >> 6;
    int q = lane >> 4, r16 = lane & 15;
    int n0 = blockIdx.x * 16;

    float msum = 0.f;
    #pragma unroll
    for (int cam = 0; cam < NCAMS; cam++) msum += maskf[cam*NQ + n0 + r16];
    float inv = 1.f / fmaxf(msum, 1.f);

    f32x4 acc[4];
    #pragma unroll
    for (int i = 0; i < 4; i++) acc[i] = (f32x4){0.f,0.f,0.f,0.f};

    const float* srow = slots + (size_t)(n0 + r16)*CH;
    for (int kc = 0; kc < 8; kc++) {
        f32x4 a0 = *reinterpret_cast<const f32x4*>(srow + kc*32 + q*8);
        f32x4 a1 = *reinterpret_cast<const f32x4*>(srow + kc*32 + q*8 + 4);
        bf16x8 afr;
        #pragma unroll
        for (int i = 0; i < 4; i++) { afr[i] = (bf16)(a0[i]*inv); afr[4+i] = (bf16)(a1[i]*inv); }
        #pragma unroll
        for (int nf = 0; nf < 4; nf++) {
            bf16x8 bfr = *reinterpret_cast<const bf16x8*>(Wop + ((size_t)(kc*16 + w*4 + nf)*64 + lane)*8);
            acc[nf] = __builtin_amdgcn_mfma_f32_16x16x32_bf16(afr, bfr, acc[nf], 0, 0, 0);
        }
    }
    #pragma unroll
    for (int nf = 0; nf < 4; nf++) {
        int c = (w*4 + nf)*16 + r16;
        float bias = b_out[c];
        #pragma unroll
        for (int r = 0; r < 4; r++) {
            int m = q*4 + r;
            yb[m][c] = acc[nf][r] + bias + feature[(size_t)(n0+m)*CH + c];
        }
    }
    __syncthreads();
    // LN: row = t>>4 (16 rows), l16 = t&15 each sums 16 elements
    int row = t >> 4, l16 = t & 15;
    int c0 = l16 * 16;
    float s = 0.f, s2 = 0.f;
    #pragma unroll
    for (int j = 0; j < 16; j++) {
        float v = yb[row][c0 + j];
        s += v; s2 += v*v;
    }
    #pragma unroll
    for (int off = 1; off < 16; off <<= 1) {
        s  += __shfl_xor(s, off);
        s2 += __shfl_xor(s2, off);
    }
    float mu = s / 256.f;
    float rsig = rsqrtf(s2 / 256.f - mu*mu + 1e-5f);
    float* orow = out + (size_t)(n0 + row)*CH + c0;
    #pragma unroll
    for (int j4 = 0; j4 < 4; j4++) {
        f32x4 o;
        #pragma unroll
        for (int i = 0; i < 4; i++) {
            int c = c0 + j4*4 + i;
            o[i] = (yb[row][c] - mu) * rsig * ln_g[c] + ln_b[c];
        }
        *reinterpret_cast<f32x4*>(orow + j4*4) = o;
    }
}

// ---------------------------------------------------------------- launch
extern "C" void kernel_launch(void* const* d_in, const int* in_sizes, int n_in,
                              void* d_out, int out_size, void* d_ws, size_t ws_size,
                              hipStream_t stream)
{
    const float* means       = (const float*)d_in[0];
    const float* feature     = (const float*)d_in[1];
    const float* feat0       = (const float*)d_in[2];
    const float* feat1       = (const float*)d_in[3];
    const float* feat2       = (const float*)d_in[4];
    const float* cam2ego     = (const float*)d_in[5];
    const float* intrins     = (const float*)d_in[6];
    const float* post_rots   = (const float*)d_in[7];
    const float* post_trans  = (const float*)d_in[8];
    const float* W_off       = (const float*)d_in[9];
    const float* b_off       = (const float*)d_in[10];
    const float* W_attn      = (const float*)d_in[11];
    const float* b_attn      = (const float*)d_in[12];
    const float* W_val       = (const float*)d_in[13];
    const float* b_val       = (const float*)d_in[14];
    const float* W_out       = (const float*)d_in[15];
    const float* b_out       = (const float*)d_in[16];
    const float* cams_embeds = (const float*)d_in[17];
    const float* level_embeds= (const float*)d_in[18];
    const float* ln_g        = (const float*)d_in[19];
    const float* ln_b        = (const float*)d_in[20];
    const int*   img_h       = (const int*)d_in[21];
    const int*   img_w       = (const int*)d_in[22];

    // workspace layout (total 65,275,904 B = 62.3 MiB)
    // NOTE: value is deliberately NOT last -- k_msda's x-pair loads may read up to 64B past the
    // final value row (weight-0 lanes at image borders); slots follows so the read stays in-bounds.
    char* ws = (char*)d_ws;
    float* coor  = (float*)(ws + 0);           //  6*6400*2 f32      =   307,200
    float* maskf = (float*)(ws + 307200);      //  6*6400 f32        =   153,600
    float* offs  = (float*)(ws + 460800);      //  6400*384 f32      = 9,830,400
    bf16*  attn  = (bf16*) (ws + 10291200);    //  6400*192 bf16     = 2,457,600
    bf16*  Wvp   = (bf16*) (ws + 12748800);    //  256*256 bf16      =   131,072
    bf16*  Woap  = (bf16*) (ws + 12879872);    //  256*576 bf16      =   294,912
    bf16*  Wop   = (bf16*) (ws + 13174784);    //  256*256 bf16      =   131,072
    bf16*  value = (bf16*) (ws + 13305856);    //  6*8*14784*32 bf16 = 45,416,448
    float* slots = (float*)(ws + 58722304);    //  6400*256 f32      = 6,553,600
    if (ws_size < 65275904u) return;

    k_prep    <<<286, 256, 0, stream>>>(means, cam2ego, intrins, post_rots, post_trans,
                                        img_h, img_w, W_val, W_off, W_attn, W_out,
                                        coor, maskf, Wvp, Woap, Wop);
    k_offattn2<<<400, 256, 0, stream>>>(feature, Woap, b_off, b_attn, offs, attn);
    k_valproj <<<1386, 256, 0, stream>>>(feat0, feat1, feat2, cams_embeds, level_embeds, Wvp, b_val, value);
    k_msda    <<<6400, 256, 0, stream>>>(coor, offs, attn, value, maskf, slots);
    k_final2  <<<400, 256, 0, stream>>>(slots, maskf, Wop, b_out, feature, ln_g, ln_b, (float*)d_out);
}